// Round 22
// baseline (941.034 us; speedup 1.0000x reference)
//
#include <hip/hip_runtime.h>
#include <math.h>

// Problem constants (fixed by the reference setup)
#define B_SZ   64
#define C_SZ   12
#define T_SZ   2048
#define K_SZ   2048
#define LMAX   11
#define CMAX   11     // C-1
#define NPAIR  6      // channel pairs: ceil(12/2), padded with zero-weight
#define PL_PAD 1024
#define A_PARAM 7.0f

#define NW     8      // waves per block
#define BLOCK_MAIN (NW * 64)
#define R      8      // outputs per thread item (dilation-strided register tile)
#define SPL    16     // wave-items per kernel (32768 items total)
#define NBLK   1024   // queue blocks (extras drain instantly)

typedef _Float16 h2 __attribute__((ext_vector_type(2)));

// Pure register bitcast — NO union (unions defeat SROA -> scratch arrays).
__device__ __forceinline__ float fdot2f(unsigned w, unsigned v, float acc) {
    return __builtin_amdgcn_fdot2(__builtin_bit_cast(h2, w),
                                  __builtin_bit_cast(h2, v), acc, false);
}

// ---------------------------------------------------------------------------
// Transpose to fp16: xT[c][t][b] = fp16(x[b][c][t]). 3.15 MB -> per-XCD L2.
__global__ __launch_bounds__(256) void trh_kernel(const float* __restrict__ x,
                                                  unsigned short* __restrict__ xT) {
    const int c    = blockIdx.x;
    const int lane = threadIdx.x & 63;
    const int wid  = threadIdx.x >> 6;
    const int t0   = blockIdx.y * 128 + wid * 32;
    const float* xrow = x + ((size_t)lane * C_SZ + c) * T_SZ + t0;
    unsigned short* dst = xT + ((size_t)c * T_SZ + t0) * 64 + lane;
    #pragma unroll 8
    for (int i = 0; i < 32; ++i) {
        const _Float16 h = (_Float16)xrow[i];
        dst[i * 64] = __builtin_bit_cast(unsigned short, h);
    }
}

// ---------------------------------------------------------------------------
// Schedule: cost[k] ~ n*L*ceil(olen/128); bitonic sort descending (heavy
// first). Also: meta[k] = n | (L<<8), and zero the work-queue counter.
__global__ __launch_bounds__(1024) void sched_kernel(const float* __restrict__ w,
                                                     const int* __restrict__ olens,
                                                     unsigned* __restrict__ perm,
                                                     unsigned* __restrict__ meta,
                                                     unsigned* __restrict__ counter) {
    __shared__ unsigned key[K_SZ];
    const int tid = threadIdx.x;
    if (tid == 0) *counter = 0u;

    for (int k = tid; k < K_SZ; k += 1024) {
        const float* wk = w + (size_t)k * (CMAX * LMAX);
        int n = 0, L = 0;
        for (int e = 0; e < CMAX * LMAX; ++e) {
            if (wk[e] != 0.0f) {
                const int c = e / LMAX, l = e % LMAX;
                n = max(n, c + 1);
                L = max(L, l + 1);
            }
        }
        meta[k] = (unsigned)n | ((unsigned)L << 8);
        const unsigned cost = (unsigned)(n * L) * (unsigned)((olens[k] + 127) >> 7);
        key[k] = (cost << 11) | (unsigned)k;
    }
    __syncthreads();

    for (int ksz = 2; ksz <= K_SZ; ksz <<= 1) {
        for (int j = ksz >> 1; j > 0; j >>= 1) {
            for (int i = tid; i < K_SZ; i += 1024) {
                const int ixj = i ^ j;
                if (ixj > i) {
                    const unsigned a = key[i], b = key[ixj];
                    const bool sw = ((i & ksz) == 0) ? (a < b) : (a > b); // descending
                    if (sw) { key[i] = b; key[ixj] = a; }
                }
            }
            __syncthreads();
        }
    }
    for (int i = tid; i < K_SZ; i += 1024)
        perm[i] = key[i] & 0x7FFu;
}

// ---------------------------------------------------------------------------
// R18's proven channel-pair dot2 inner loop (SALU-bumped uniform pointers,
// all-'unsigned' arrays). Executed by ONE wave per item: units u = sp mod SPL.
template<int LC>
__device__ __forceinline__ void conv_all(
    const unsigned short* __restrict__ xT,
    const int*      __restrict__ sCh,          // 12 entries (zero-padded)
    const unsigned* __restrict__ sWp,          // [NPAIR*LMAX] packed h2 pairs
    int npair, int d, int offr, int olen, float bias, int sp,
    int lane, float& psum, float& pmax)
{
    constexpr int NV = R + LC - 1;        // tap positions spanned by one item

    const int nj   = (olen + d - 1) / d;          // outputs per residue chain
    const int njb  = (nj + R - 1) / R;            // items per chain
    const int S    = (d >= 64) ? 1 : ((64 + d - 1) / d);
    const int len  = (njb + S - 1) / S;
    const int nunits = d * S;                     // always >= 64 > SPL

    for (int u = sp; u < nunits; u += SPL) {
        int q, seg;
        if (S == 1) { q = u; seg = 0; }
        else        { q = u % d; seg = u / d; }   // wave-uniform div
        const int jb0 = seg * len;
        const int jb1 = min(njb, jb0 + len);

        for (int jb = jb0; jb < jb1; ++jb) {
            const int tq = q + jb * (R * d);      // first output t of this item
            if (tq >= olen) break;
            const int tpos0 = tq + offr;          // real x coord of tap 0

            float y[R];
            #pragma unroll
            for (int r = 0; r < R; ++r) y[r] = bias;

            const bool fast = (tpos0 >= 0) && (tpos0 + (NV - 1) * d < T_SZ);

            if (fast) {
                for (int p = 0; p < npair; ++p) {
                    const int rbA = __builtin_amdgcn_readfirstlane(sCh[2*p  ] * T_SZ + tpos0);
                    const int rbB = __builtin_amdgcn_readfirstlane(sCh[2*p+1] * T_SZ + tpos0);
                    const unsigned short* rpA = xT + ((size_t)rbA << 6);  // uniform ptrs
                    const unsigned short* rpB = xT + ((size_t)rbB << 6);

                    unsigned vp[NV];
                    #pragma unroll
                    for (int i = 0; i < NV; ++i) {
                        const unsigned a = rpA[lane];                 // saddr + lane*2
                        const unsigned b = rpB[lane];
                        vp[i] = __builtin_amdgcn_perm(b, a, 0x05040100); // {a,b}
                        rpA += (d << 6); rpB += (d << 6);             // SALU bumps
                    }

                    const unsigned* wrow = &sWp[p * LMAX];
                    #pragma unroll
                    for (int l = 0; l < LC; ++l) {
                        const unsigned w = wrow[l];                   // LDS broadcast
                        #pragma unroll
                        for (int r = 0; r < R; ++r)
                            y[r] = fdot2f(w, vp[l + r], y[r]);
                    }
                }
            } else {
                for (int p = 0; p < npair; ++p) {
                    const int rbA = __builtin_amdgcn_readfirstlane(sCh[2*p  ] * T_SZ);
                    const int rbB = __builtin_amdgcn_readfirstlane(sCh[2*p+1] * T_SZ);
                    const unsigned short* rowA = xT + ((size_t)rbA << 6);
                    const unsigned short* rowB = xT + ((size_t)rbB << 6);

                    unsigned vp[NV];
                    #pragma unroll
                    for (int i = 0; i < NV; ++i) {
                        const int tp  = tpos0 + i * d;                // wave-uniform
                        const int tpc = min(max(tp, 0), T_SZ - 1);
                        const unsigned a = rowA[((size_t)tpc << 6) + lane];
                        const unsigned b = rowB[((size_t)tpc << 6) + lane];
                        const unsigned pk = __builtin_amdgcn_perm(b, a, 0x05040100);
                        vp[i] = ((unsigned)tp < (unsigned)T_SZ) ? pk : 0u;
                    }

                    const unsigned* wrow = &sWp[p * LMAX];
                    #pragma unroll
                    for (int l = 0; l < LC; ++l) {
                        const unsigned w = wrow[l];
                        #pragma unroll
                        for (int r = 0; r < R; ++r)
                            y[r] = fdot2f(w, vp[l + r], y[r]);
                    }
                }
            }

            #pragma unroll
            for (int r = 0; r < R; ++r) {
                const int t = tq + r * d;
                if (t < olen) {                   // wave-uniform branch
                    psum += 1.0f / (1.0f + __expf(3.0f - A_PARAM * y[r]));
                    pmax  = fmaxf(pmax, y[r]);
                }
            }
        }
    }
}

// ---------------------------------------------------------------------------
// WAVE-granular persistent queue: one wave = one (k, sp) item. No
// __syncthreads in the loop — lane0 pops, __shfl broadcasts, each wave packs
// weights into its PRIVATE LDS slot (same-wave lgkmcnt ordering only), and
// writes its 128 partials directly (lane = batch, no cross-wave reduce).
__global__ __launch_bounds__(BLOCK_MAIN, 4) void rocket_tr(
    const unsigned short* __restrict__ xT,   // (C, T, 64) fp16 bits
    const unsigned* __restrict__ perm,       // heavy-first sorted k map
    const unsigned* __restrict__ meta,       // n | (L<<8) per k
    const float* __restrict__ weights,       // (K, CMAX, LMAX)
    const float* __restrict__ biases,
    const int*   __restrict__ ch_idx,        // (K, CMAX)
    const int*   __restrict__ dils,
    const int*   __restrict__ offs,
    const int*   __restrict__ olens,
    float*       __restrict__ part,          // (K, SPL, 128) partials
    unsigned*    __restrict__ counter)
{
    __shared__ unsigned sWpAll[NW][NPAIR * LMAX];  // per-wave weight slots
    __shared__ int      sChAll[NW][12];            // per-wave channel slots

    const int tid  = threadIdx.x;
    const int lane = tid & 63;
    const int wid  = __builtin_amdgcn_readfirstlane(tid >> 6);
    unsigned* sWp = &sWpAll[wid][0];
    int*      sCh = &sChAll[wid][0];

    for (;;) {
        int item = 0;
        if (lane == 0) item = (int)atomicAdd(counter, 1u);
        item = __shfl(item, 0, 64);           // broadcast lane0's pop
        if (item >= K_SZ * SPL) break;        // wave-uniform exit

        const int kidx = item / SPL;          // sorted position (heavy first)
        const int sp   = item % SPL;
        const int k    = (int)perm[kidx];

        // Pack weights into this wave's LDS slot. NPAIR*LMAX = 66 > 64 lanes,
        // so STRIDE the loop (R21 bug: 'if (lane < 66)' left entries 64,65
        // unwritten -> poisoned weights for pair 5 taps 9,10).
        for (int e = lane; e < NPAIR * LMAX; e += 64) {
            const int p = e / LMAX;
            const int l = e % LMAX;
            const float wA = weights[(size_t)k * (CMAX * LMAX) + (2 * p) * LMAX + l];
            const float wB = (2 * p + 1 < CMAX)
                ? weights[(size_t)k * (CMAX * LMAX) + (2 * p + 1) * LMAX + l] : 0.0f;
            h2 hh; hh.x = (_Float16)wA; hh.y = (_Float16)wB;
            sWp[e] = __builtin_bit_cast(unsigned, hh);
        }
        if (lane < 12)
            sCh[lane] = (lane < CMAX) ? ch_idx[(size_t)k * CMAX + lane] : 0;
        // Same-wave LDS write->read ordering: drain LDS ops, pin the order.
        asm volatile("s_waitcnt lgkmcnt(0)" ::: "memory");
        __builtin_amdgcn_sched_barrier(0);

        const unsigned mk = meta[k];
        const int   n     = (int)(mk & 0xFFu);
        const int   L     = (int)((mk >> 8) & 0xFFu);
        const int   npair = (n + 1) >> 1;
        const int   d     = dils[k];
        const int   offr  = offs[k] - PL_PAD;
        const int   olen  = olens[k];
        const float bias  = biases[k];

        float psum = 0.0f;
        float pmax = -INFINITY;

        if (L <= 7)
            conv_all<7 >(xT, sCh, sWp, npair, d, offr, olen, bias, sp, lane, psum, pmax);
        else if (L <= 9)
            conv_all<9 >(xT, sCh, sWp, npair, d, offr, olen, bias, sp, lane, psum, pmax);
        else
            conv_all<11>(xT, sCh, sWp, npair, d, offr, olen, bias, sp, lane, psum, pmax);

        float* pp = part + ((size_t)k * SPL + sp) * 128;
        pp[lane]      = psum;    // partial sigmoid-sum for batch 'lane'
        pp[64 + lane] = pmax;    // partial max for batch 'lane'
    }
}

// ---------------------------------------------------------------------------
// Deterministic combine: out[b][2k] = (sum_sp psum)/olen, out[b][2k+1] = max.
__global__ __launch_bounds__(256) void combine_kernel(
    const float* __restrict__ part,          // (K, SPL, 128)
    const int*   __restrict__ olens,
    float*       __restrict__ out)           // (B, 2K)
{
    const int idx = blockIdx.x * 256 + threadIdx.x;   // [0, K*64)
    if (idx >= K_SZ * 64) return;
    const int k = idx >> 6;
    const int b = idx & 63;
    const float* pp = part + (size_t)k * SPL * 128;
    float s = 0.0f, m = -INFINITY;
    #pragma unroll 4
    for (int sp = 0; sp < SPL; ++sp) {
        s += pp[sp * 128 + b];
        m  = fmaxf(m, pp[sp * 128 + 64 + b]);
    }
    out[(size_t)b * (2 * K_SZ) + 2 * k]     = s / (float)olens[k];
    out[(size_t)b * (2 * K_SZ) + 2 * k + 1] = m;
}

// ---------------------------------------------------------------------------
// Fallback (ws too small): simple checked-gather kernel, known correct.
__global__ __launch_bounds__(256) void rocket_fallback(
    const float* __restrict__ x,
    const float* __restrict__ weights,
    const float* __restrict__ biases,
    const int*   __restrict__ ch_idx,
    const int*   __restrict__ dils,
    const int*   __restrict__ offs,
    const int*   __restrict__ olens,
    float*       __restrict__ out)
{
    __shared__ float sW[CMAX][LMAX];
    __shared__ int   sCh[CMAX];
    __shared__ float sRed[2][4];

    const int k   = blockIdx.x;
    const int tid = threadIdx.x;

    if (tid < CMAX * LMAX)
        sW[tid / LMAX][tid % LMAX] = weights[(size_t)k * (CMAX * LMAX) + tid];
    if (tid < CMAX)
        sCh[tid] = ch_idx[(size_t)k * CMAX + tid];
    __syncthreads();

    const int   d    = dils[k];
    const int   off  = offs[k] - PL_PAD;
    const int   olen = olens[k];
    const float bias = biases[k];
    const int   lane = tid & 63;
    const int   wid  = tid >> 6;

    for (int b = blockIdx.y; b < B_SZ; b += gridDim.y) {
        float psum = 0.0f, pmax = -INFINITY;
        for (int t = tid; t < T_SZ; t += 256) {
            float y = bias;
            for (int c = 0; c < CMAX; ++c) {
                const float* xb = x + ((size_t)b * C_SZ + sCh[c]) * T_SZ;
                int pos = off + t;
                for (int l = 0; l < LMAX; ++l) {
                    const float xv = ((unsigned)pos < (unsigned)T_SZ) ? xb[pos] : 0.0f;
                    y = fmaf(sW[c][l], xv, y);
                    pos += d;
                }
            }
            if (t < olen) {
                psum += 1.0f / (1.0f + __expf(3.0f - A_PARAM * y));
                pmax = fmaxf(pmax, y);
            }
        }
        for (int o = 32; o > 0; o >>= 1) {
            psum += __shfl_down(psum, o, 64);
            pmax  = fmaxf(pmax, __shfl_down(pmax, o, 64));
        }
        if (lane == 0) { sRed[0][wid] = psum; sRed[1][wid] = pmax; }
        __syncthreads();
        if (tid == 0) {
            const float s = sRed[0][0] + sRed[0][1] + sRed[0][2] + sRed[0][3];
            const float m = fmaxf(fmaxf(sRed[1][0], sRed[1][1]),
                                  fmaxf(sRed[1][2], sRed[1][3]));
            out[(size_t)b * (2 * K_SZ) + 2 * k]     = s / (float)olen;
            out[(size_t)b * (2 * K_SZ) + 2 * k + 1] = m;
        }
        __syncthreads();
    }
}

// ---------------------------------------------------------------------------
extern "C" void kernel_launch(void* const* d_in, const int* in_sizes, int n_in,
                              void* d_out, int out_size, void* d_ws, size_t ws_size,
                              hipStream_t stream) {
    const float* x       = (const float*)d_in[0];
    const float* weights = (const float*)d_in[1];
    const float* biases  = (const float*)d_in[2];
    const int*   ch_idx  = (const int*)  d_in[3];
    const int*   dils    = (const int*)  d_in[4];
    const int*   offs    = (const int*)  d_in[5];
    const int*   olens   = (const int*)  d_in[6];
    float*       out     = (float*)d_out;

    const size_t xt_bytes   = (size_t)C_SZ * T_SZ * 64 * sizeof(unsigned short); // 3.15 MB
    const size_t perm_bytes = K_SZ * sizeof(unsigned);
    const size_t meta_bytes = K_SZ * sizeof(unsigned);
    const size_t part_bytes = (size_t)K_SZ * SPL * 128 * sizeof(float);          // 16.8 MB
    const size_t need       = xt_bytes + perm_bytes + meta_bytes + part_bytes + 128;

    if (ws_size >= need) {
        char* wsb = (char*)d_ws;
        unsigned short* xT   = (unsigned short*)wsb;
        unsigned* perm       = (unsigned*)(wsb + xt_bytes);
        unsigned* meta       = (unsigned*)(wsb + xt_bytes + perm_bytes);
        float*    part       = (float*)(wsb + xt_bytes + perm_bytes + meta_bytes);
        unsigned* counter    = (unsigned*)(wsb + xt_bytes + perm_bytes + meta_bytes + part_bytes);

        dim3 tgrid(C_SZ, T_SZ / 128);
        trh_kernel<<<tgrid, 256, 0, stream>>>(x, xT);
        sched_kernel<<<1, 1024, 0, stream>>>(weights, olens, perm, meta, counter);
        rocket_tr<<<NBLK, BLOCK_MAIN, 0, stream>>>(xT, perm, meta, weights,
                                                   biases, ch_idx, dils, offs,
                                                   olens, part, counter);
        combine_kernel<<<(K_SZ * 64 + 255) / 256, 256, 0, stream>>>(part, olens, out);
    } else {
        dim3 grid(K_SZ, 16);
        rocket_fallback<<<grid, 256, 0, stream>>>(x, weights, biases, ch_idx,
                                                  dils, offs, olens, out);
    }
}

// Round 23
// 629.906 us; speedup vs baseline: 1.4939x; 1.4939x over previous
//
#include <hip/hip_runtime.h>
#include <math.h>

// Problem constants (fixed by the reference setup)
#define B_SZ   64
#define C_SZ   12
#define T_SZ   2048
#define K_SZ   2048
#define LMAX   11
#define CMAX   11     // C-1
#define NPAIR  6      // channel pairs: ceil(12/2), padded with zero-weight
#define PL_PAD 1024
#define A_PARAM 7.0f

#define NW     8      // waves per block in main kernel
#define BLOCK_MAIN (NW * 64)
#define R      8      // outputs per thread item (dilation-strided register tile)
#define SPL    4      // chain-splits per kernel (8192 work items)
#define NBLK   1024   // persistent blocks: 4/CU x 256 CU

typedef _Float16 h2 __attribute__((ext_vector_type(2)));

// Pure register bitcast — NO union (unions defeat SROA -> scratch arrays).
__device__ __forceinline__ float fdot2f(unsigned w, unsigned v, float acc) {
    return __builtin_amdgcn_fdot2(__builtin_bit_cast(h2, w),
                                  __builtin_bit_cast(h2, v), acc, false);
}

// ---------------------------------------------------------------------------
// Transpose to fp16: xT[c][t][b] = fp16(x[b][c][t]). 3.15 MB -> per-XCD L2.
__global__ __launch_bounds__(256) void trh_kernel(const float* __restrict__ x,
                                                  unsigned short* __restrict__ xT) {
    const int c    = blockIdx.x;
    const int lane = threadIdx.x & 63;
    const int wid  = threadIdx.x >> 6;
    const int t0   = blockIdx.y * 128 + wid * 32;
    const float* xrow = x + ((size_t)lane * C_SZ + c) * T_SZ + t0;
    unsigned short* dst = xT + ((size_t)c * T_SZ + t0) * 64 + lane;
    #pragma unroll 8
    for (int i = 0; i < 32; ++i) {
        const _Float16 h = (_Float16)xrow[i];
        dst[i * 64] = __builtin_bit_cast(unsigned short, h);
    }
}

// ---------------------------------------------------------------------------
// Schedule: cost[k] ~ n*L*ceil(olen/128); bitonic sort descending (heavy
// first). Also: meta[k] = n | (L<<8), and zero the work-queue counter.
__global__ __launch_bounds__(1024) void sched_kernel(const float* __restrict__ w,
                                                     const int* __restrict__ olens,
                                                     unsigned* __restrict__ perm,
                                                     unsigned* __restrict__ meta,
                                                     unsigned* __restrict__ counter) {
    __shared__ unsigned key[K_SZ];
    const int tid = threadIdx.x;
    if (tid == 0) *counter = 0u;

    for (int k = tid; k < K_SZ; k += 1024) {
        const float* wk = w + (size_t)k * (CMAX * LMAX);
        int n = 0, L = 0;
        for (int e = 0; e < CMAX * LMAX; ++e) {
            if (wk[e] != 0.0f) {
                const int c = e / LMAX, l = e % LMAX;
                n = max(n, c + 1);
                L = max(L, l + 1);
            }
        }
        meta[k] = (unsigned)n | ((unsigned)L << 8);
        const unsigned cost = (unsigned)(n * L) * (unsigned)((olens[k] + 127) >> 7);
        key[k] = (cost << 11) | (unsigned)k;
    }
    __syncthreads();

    for (int ksz = 2; ksz <= K_SZ; ksz <<= 1) {
        for (int j = ksz >> 1; j > 0; j >>= 1) {
            for (int i = tid; i < K_SZ; i += 1024) {
                const int ixj = i ^ j;
                if (ixj > i) {
                    const unsigned a = key[i], b = key[ixj];
                    const bool sw = ((i & ksz) == 0) ? (a < b) : (a > b); // descending
                    if (sw) { key[i] = b; key[ixj] = a; }
                }
            }
            __syncthreads();
        }
    }
    for (int i = tid; i < K_SZ; i += 1024)
        perm[i] = key[i] & 0x7FFu;
}

// ---------------------------------------------------------------------------
// R17's proven inner loop (channel-pair dot2, SALU-bumped uniform pointers,
// all-'unsigned' arrays). Unit space interleaved across SPL splits.
template<int LC>
__device__ __forceinline__ void conv_all(
    const unsigned short* __restrict__ xT,
    const int*      __restrict__ sCh,          // 12 entries (zero-padded)
    const unsigned  (* __restrict__ sWp)[LMAX],// [NPAIR][LMAX] packed h2 pairs
    int npair, int d, int offr, int olen, float bias, int sp,
    int lane, int wid, float& psum, float& pmax)
{
    constexpr int NV = R + LC - 1;        // tap positions spanned by one item

    const int nj   = (olen + d - 1) / d;          // outputs per residue chain
    const int njb  = (nj + R - 1) / R;            // items per chain
    const int S    = (d >= 64) ? 1 : ((64 + d - 1) / d);
    const int len  = (njb + S - 1) / S;
    const int nunits = d * S;

    for (int u = sp * NW + wid; u < nunits; u += NW * SPL) {
        int q, seg;
        if (S == 1) { q = u; seg = 0; }
        else        { q = u % d; seg = u / d; }   // wave-uniform div
        const int jb0 = seg * len;
        const int jb1 = min(njb, jb0 + len);

        for (int jb = jb0; jb < jb1; ++jb) {
            const int tq = q + jb * (R * d);      // first output t of this item
            if (tq >= olen) break;
            const int tpos0 = tq + offr;          // real x coord of tap 0

            float y[R];
            #pragma unroll
            for (int r = 0; r < R; ++r) y[r] = bias;

            const bool fast = (tpos0 >= 0) && (tpos0 + (NV - 1) * d < T_SZ);

            if (fast) {
                for (int p = 0; p < npair; ++p) {
                    const int rbA = __builtin_amdgcn_readfirstlane(sCh[2*p  ] * T_SZ + tpos0);
                    const int rbB = __builtin_amdgcn_readfirstlane(sCh[2*p+1] * T_SZ + tpos0);
                    const unsigned short* rpA = xT + ((size_t)rbA << 6);  // uniform ptrs
                    const unsigned short* rpB = xT + ((size_t)rbB << 6);

                    unsigned vp[NV];
                    #pragma unroll
                    for (int i = 0; i < NV; ++i) {
                        const unsigned a = rpA[lane];                 // saddr + lane*2
                        const unsigned b = rpB[lane];
                        vp[i] = __builtin_amdgcn_perm(b, a, 0x05040100); // {a,b}
                        rpA += (d << 6); rpB += (d << 6);             // SALU bumps
                    }

                    const unsigned* wrow = &sWp[p][0];
                    #pragma unroll
                    for (int l = 0; l < LC; ++l) {
                        const unsigned w = wrow[l];                   // LDS broadcast
                        #pragma unroll
                        for (int r = 0; r < R; ++r)
                            y[r] = fdot2f(w, vp[l + r], y[r]);
                    }
                }
            } else {
                for (int p = 0; p < npair; ++p) {
                    const int rbA = __builtin_amdgcn_readfirstlane(sCh[2*p  ] * T_SZ);
                    const int rbB = __builtin_amdgcn_readfirstlane(sCh[2*p+1] * T_SZ);
                    const unsigned short* rowA = xT + ((size_t)rbA << 6);
                    const unsigned short* rowB = xT + ((size_t)rbB << 6);

                    unsigned vp[NV];
                    #pragma unroll
                    for (int i = 0; i < NV; ++i) {
                        const int tp  = tpos0 + i * d;                // wave-uniform
                        const int tpc = min(max(tp, 0), T_SZ - 1);
                        const unsigned a = rowA[((size_t)tpc << 6) + lane];
                        const unsigned b = rowB[((size_t)tpc << 6) + lane];
                        const unsigned pk = __builtin_amdgcn_perm(b, a, 0x05040100);
                        vp[i] = ((unsigned)tp < (unsigned)T_SZ) ? pk : 0u;
                    }

                    const unsigned* wrow = &sWp[p][0];
                    #pragma unroll
                    for (int l = 0; l < LC; ++l) {
                        const unsigned w = wrow[l];
                        #pragma unroll
                        for (int r = 0; r < R; ++r)
                            y[r] = fdot2f(w, vp[l + r], y[r]);
                    }
                }
            }

            #pragma unroll
            for (int r = 0; r < R; ++r) {
                const int t = tq + r * d;
                if (t < olen) {                   // wave-uniform branch
                    psum += 1.0f / (1.0f + __expf(3.0f - A_PARAM * y[r]));
                    pmax  = fmaxf(pmax, y[r]);
                }
            }
        }
    }
}

// ---------------------------------------------------------------------------
// Persistent work-queue main kernel: NBLK resident blocks pop (kidx, sp)
// items heavy-first from an atomic counter. Each item writes its own partial
// slot -> deterministic regardless of which block executes it.
__global__ __launch_bounds__(BLOCK_MAIN, 4) void rocket_tr(
    const unsigned short* __restrict__ xT,   // (C, T, 64) fp16 bits
    const unsigned* __restrict__ perm,       // heavy-first sorted k map
    const unsigned* __restrict__ meta,       // n | (L<<8) per k
    const float* __restrict__ weights,       // (K, CMAX, LMAX)
    const float* __restrict__ biases,
    const int*   __restrict__ ch_idx,        // (K, CMAX)
    const int*   __restrict__ dils,
    const int*   __restrict__ offs,
    const int*   __restrict__ olens,
    float*       __restrict__ part,          // (K, SPL, 128) partials
    unsigned*    __restrict__ counter)
{
    __shared__ unsigned sWp[NPAIR][LMAX];    // packed {W[2p][l], W[2p+1][l]}
    __shared__ int      sCh[2 * NPAIR];
    __shared__ int      sItem;
    __shared__ float    sP[NW][64];
    __shared__ float    sM[NW][64];

    const int tid  = threadIdx.x;
    const int lane = tid & 63;
    const int wid  = __builtin_amdgcn_readfirstlane(tid >> 6);

    for (;;) {
        __syncthreads();                      // protect sItem/sWp/sCh/sP reuse
        if (tid == 0) sItem = (int)atomicAdd(counter, 1u);
        __syncthreads();
        const int item = sItem;
        if (item >= K_SZ * SPL) break;        // uniform exit

        const int kidx = item / SPL;          // sorted position (heavy first)
        const int sp   = item % SPL;
        const int k    = (int)perm[kidx];

        // Pack weights straight from global (66 threads), channels (12).
        if (tid < NPAIR * LMAX) {
            const int p = tid / LMAX;
            const int l = tid % LMAX;
            const float wA = weights[(size_t)k * (CMAX * LMAX) + (2 * p) * LMAX + l];
            const float wB = (2 * p + 1 < CMAX)
                ? weights[(size_t)k * (CMAX * LMAX) + (2 * p + 1) * LMAX + l] : 0.0f;
            h2 hh; hh.x = (_Float16)wA; hh.y = (_Float16)wB;
            sWp[p][l] = __builtin_bit_cast(unsigned, hh);
        }
        if (tid >= 64 && tid < 64 + 2 * NPAIR) {
            const int c = tid - 64;
            sCh[c] = (c < CMAX) ? ch_idx[(size_t)k * CMAX + c] : 0;
        }
        __syncthreads();

        const unsigned mk = meta[k];
        const int   n     = (int)(mk & 0xFFu);
        const int   L     = (int)((mk >> 8) & 0xFFu);
        const int   npair = (n + 1) >> 1;
        const int   d     = dils[k];
        const int   offr  = offs[k] - PL_PAD;
        const int   olen  = olens[k];
        const float bias  = biases[k];

        float psum = 0.0f;
        float pmax = -INFINITY;

        if (L <= 7)
            conv_all<7 >(xT, sCh, sWp, npair, d, offr, olen, bias, sp, lane, wid, psum, pmax);
        else if (L <= 9)
            conv_all<9 >(xT, sCh, sWp, npair, d, offr, olen, bias, sp, lane, wid, psum, pmax);
        else
            conv_all<11>(xT, sCh, sWp, npair, d, offr, olen, bias, sp, lane, wid, psum, pmax);

        sP[wid][lane] = psum;
        sM[wid][lane] = pmax;
        __syncthreads();

        if (tid < 64) {
            float s = 0.0f, m = -INFINITY;
            #pragma unroll
            for (int w = 0; w < NW; ++w) {
                s += sP[w][tid];
                m  = fmaxf(m, sM[w][tid]);
            }
            float* pp = part + ((size_t)k * SPL + sp) * 128;
            pp[tid]      = s;     // partial sigmoid-sum for batch tid
            pp[64 + tid] = m;     // partial max for batch tid
        }
    }
}

// ---------------------------------------------------------------------------
// Deterministic combine: out[b][2k] = (sum_sp psum)/olen, out[b][2k+1] = max.
__global__ __launch_bounds__(256) void combine_kernel(
    const float* __restrict__ part,          // (K, SPL, 128)
    const int*   __restrict__ olens,
    float*       __restrict__ out)           // (B, 2K)
{
    const int idx = blockIdx.x * 256 + threadIdx.x;   // [0, K*64)
    if (idx >= K_SZ * 64) return;
    const int k = idx >> 6;
    const int b = idx & 63;
    const float* pp = part + (size_t)k * SPL * 128;
    float s = 0.0f, m = -INFINITY;
    #pragma unroll
    for (int sp = 0; sp < SPL; ++sp) {
        s += pp[sp * 128 + b];
        m  = fmaxf(m, pp[sp * 128 + 64 + b]);
    }
    out[(size_t)b * (2 * K_SZ) + 2 * k]     = s / (float)olens[k];
    out[(size_t)b * (2 * K_SZ) + 2 * k + 1] = m;
}

// ---------------------------------------------------------------------------
// Fallback (ws too small): simple checked-gather kernel, known correct.
__global__ __launch_bounds__(256) void rocket_fallback(
    const float* __restrict__ x,
    const float* __restrict__ weights,
    const float* __restrict__ biases,
    const int*   __restrict__ ch_idx,
    const int*   __restrict__ dils,
    const int*   __restrict__ offs,
    const int*   __restrict__ olens,
    float*       __restrict__ out)
{
    __shared__ float sW[CMAX][LMAX];
    __shared__ int   sCh[CMAX];
    __shared__ float sRed[2][4];

    const int k   = blockIdx.x;
    const int tid = threadIdx.x;

    if (tid < CMAX * LMAX)
        sW[tid / LMAX][tid % LMAX] = weights[(size_t)k * (CMAX * LMAX) + tid];
    if (tid < CMAX)
        sCh[tid] = ch_idx[(size_t)k * CMAX + tid];
    __syncthreads();

    const int   d    = dils[k];
    const int   off  = offs[k] - PL_PAD;
    const int   olen = olens[k];
    const float bias = biases[k];
    const int   lane = tid & 63;
    const int   wid  = tid >> 6;

    for (int b = blockIdx.y; b < B_SZ; b += gridDim.y) {
        float psum = 0.0f, pmax = -INFINITY;
        for (int t = tid; t < T_SZ; t += 256) {
            float y = bias;
            for (int c = 0; c < CMAX; ++c) {
                const float* xb = x + ((size_t)b * C_SZ + sCh[c]) * T_SZ;
                int pos = off + t;
                for (int l = 0; l < LMAX; ++l) {
                    const float xv = ((unsigned)pos < (unsigned)T_SZ) ? xb[pos] : 0.0f;
                    y = fmaf(sW[c][l], xv, y);
                    pos += d;
                }
            }
            if (t < olen) {
                psum += 1.0f / (1.0f + __expf(3.0f - A_PARAM * y));
                pmax = fmaxf(pmax, y);
            }
        }
        for (int o = 32; o > 0; o >>= 1) {
            psum += __shfl_down(psum, o, 64);
            pmax  = fmaxf(pmax, __shfl_down(pmax, o, 64));
        }
        if (lane == 0) { sRed[0][wid] = psum; sRed[1][wid] = pmax; }
        __syncthreads();
        if (tid == 0) {
            const float s = sRed[0][0] + sRed[0][1] + sRed[0][2] + sRed[0][3];
            const float m = fmaxf(fmaxf(sRed[1][0], sRed[1][1]),
                                  fmaxf(sRed[1][2], sRed[1][3]));
            out[(size_t)b * (2 * K_SZ) + 2 * k]     = s / (float)olen;
            out[(size_t)b * (2 * K_SZ) + 2 * k + 1] = m;
        }
        __syncthreads();
    }
}

// ---------------------------------------------------------------------------
extern "C" void kernel_launch(void* const* d_in, const int* in_sizes, int n_in,
                              void* d_out, int out_size, void* d_ws, size_t ws_size,
                              hipStream_t stream) {
    const float* x       = (const float*)d_in[0];
    const float* weights = (const float*)d_in[1];
    const float* biases  = (const float*)d_in[2];
    const int*   ch_idx  = (const int*)  d_in[3];
    const int*   dils    = (const int*)  d_in[4];
    const int*   offs    = (const int*)  d_in[5];
    const int*   olens   = (const int*)  d_in[6];
    float*       out     = (float*)d_out;

    const size_t xt_bytes   = (size_t)C_SZ * T_SZ * 64 * sizeof(unsigned short); // 3.15 MB
    const size_t perm_bytes = K_SZ * sizeof(unsigned);
    const size_t meta_bytes = K_SZ * sizeof(unsigned);
    const size_t part_bytes = (size_t)K_SZ * SPL * 128 * sizeof(float);          // 4.19 MB
    const size_t need       = xt_bytes + perm_bytes + meta_bytes + part_bytes + 128;

    if (ws_size >= need) {
        char* wsb = (char*)d_ws;
        unsigned short* xT   = (unsigned short*)wsb;
        unsigned* perm       = (unsigned*)(wsb + xt_bytes);
        unsigned* meta       = (unsigned*)(wsb + xt_bytes + perm_bytes);
        float*    part       = (float*)(wsb + xt_bytes + perm_bytes + meta_bytes);
        unsigned* counter    = (unsigned*)(wsb + xt_bytes + perm_bytes + meta_bytes + part_bytes);

        dim3 tgrid(C_SZ, T_SZ / 128);
        trh_kernel<<<tgrid, 256, 0, stream>>>(x, xT);
        sched_kernel<<<1, 1024, 0, stream>>>(weights, olens, perm, meta, counter);
        rocket_tr<<<NBLK, BLOCK_MAIN, 0, stream>>>(xT, perm, meta, weights,
                                                   biases, ch_idx, dils, offs,
                                                   olens, part, counter);
        combine_kernel<<<(K_SZ * 64 + 255) / 256, 256, 0, stream>>>(part, olens, out);
    } else {
        dim3 grid(K_SZ, 16);
        rocket_fallback<<<grid, 256, 0, stream>>>(x, weights, biases, ch_idx,
                                                  dils, offs, olens, out);
    }
}